// Round 1
// baseline (3712.758 us; speedup 1.0000x reference)
//
#include <hip/hip_runtime.h>

#define N_NODES 100000
#define N_EDGES 1600000

// ---------------------------------------------------------------------------
// C[N,M] = X[N,K] @ W[K,M], fp32, 64x64 tile, BK=16, 256 threads, 4x4/thread
// ---------------------------------------------------------------------------
__global__ __launch_bounds__(256) void gemm_f32(
    const float* __restrict__ X, const float* __restrict__ W,
    float* __restrict__ C, int N, int K, int M) {
  __shared__ float Xs[16][68];  // [k][m], row stride 68*4B = multiple of 16B
  __shared__ float Ws[16][68];  // [k][n]
  const int tid = threadIdx.x;
  const int trow = tid >> 4;    // 0..15
  const int tcol = tid & 15;    // 0..15
  const int bm = blockIdx.x * 64;
  const int bn = blockIdx.y * 64;
  float acc[4][4] = {};

  for (int k0 = 0; k0 < K; k0 += 16) {
    // load X tile: 64 rows x 16 k
#pragma unroll
    for (int i = 0; i < 4; ++i) {
      int m = (tid >> 4) + i * 16;
      int k = tid & 15;
      int gm = bm + m;
      Xs[k][m] = (gm < N) ? X[(long)gm * K + (k0 + k)] : 0.f;
    }
    // load W tile: 16 k x 64 n (coalesced over n)
#pragma unroll
    for (int i = 0; i < 4; ++i) {
      int k = (tid >> 6) + i * 4;
      int n = tid & 63;
      Ws[k][n] = W[(long)(k0 + k) * M + (bn + n)];
    }
    __syncthreads();
#pragma unroll
    for (int k = 0; k < 16; ++k) {
      float xr[4], wr[4];
#pragma unroll
      for (int i = 0; i < 4; ++i) xr[i] = Xs[k][trow * 4 + i];
#pragma unroll
      for (int j = 0; j < 4; ++j) wr[j] = Ws[k][tcol * 4 + j];
#pragma unroll
      for (int i = 0; i < 4; ++i)
#pragma unroll
        for (int j = 0; j < 4; ++j)
          acc[i][j] += xr[i] * wr[j];
    }
    __syncthreads();
  }

#pragma unroll
  for (int i = 0; i < 4; ++i) {
    int gm = bm + trow * 4 + i;
    if (gm < N) {
#pragma unroll
      for (int j = 0; j < 4; ++j)
        C[(long)gm * M + (bn + tcol * 4 + j)] = acc[i][j];
    }
  }
}

// ---------------------------------------------------------------------------
// out[dst[e], :] += sup[src[e], :] * w[e]   (atomicAdd version)
// blockDim = 256; D in {128, 256}
// ---------------------------------------------------------------------------
template <int D>
__global__ __launch_bounds__(256) void scatter_add(
    const float* __restrict__ sup, const int* __restrict__ src,
    const int* __restrict__ dst, const float* __restrict__ ew,
    float* __restrict__ out) {
  constexpr int EPB = 256 / D;             // edges handled per block-iteration
  const int lane = threadIdx.x % D;
  const int sub  = threadIdx.x / D;
  for (long e = (long)blockIdx.x * EPB + sub; e < N_EDGES;
       e += (long)gridDim.x * EPB) {
    const int s = src[e];
    const int d = dst[e];
    const float w = ew[e];
    const float v = sup[(long)s * D + lane] * w;
    atomicAdd(&out[(long)d * D + lane], v);
  }
}

// ---------------------------------------------------------------------------
__global__ void zero_f32(float* __restrict__ p, long n) {
  long i = (long)blockIdx.x * blockDim.x + threadIdx.x;
  const long stride = (long)gridDim.x * blockDim.x;
  for (; i < n; i += stride) p[i] = 0.f;
}

template <int D, bool RELU>
__global__ void bias_act(float* __restrict__ h, const float* __restrict__ b) {
  const long n = (long)N_NODES * D;
  long i = (long)blockIdx.x * blockDim.x + threadIdx.x;
  const long stride = (long)gridDim.x * blockDim.x;
  for (; i < n; i += stride) {
    float v = h[i] + b[i & (D - 1)];
    h[i] = RELU ? fmaxf(v, 0.f) : v;
  }
}

// ---------------------------------------------------------------------------
extern "C" void kernel_launch(void* const* d_in, const int* in_sizes, int n_in,
                              void* d_out, int out_size, void* d_ws,
                              size_t ws_size, hipStream_t stream) {
  const float* x  = (const float*)d_in[0];
  const int*   src = (const int*)d_in[1];
  const int*   dst = (const int*)d_in[2];
  const float* ew  = (const float*)d_in[3];
  const float* W1  = (const float*)d_in[4];
  const float* b1  = (const float*)d_in[5];
  const float* W2  = (const float*)d_in[6];
  const float* b2  = (const float*)d_in[7];
  const float* W3  = (const float*)d_in[8];
  const float* b3  = (const float*)d_in[9];
  float* out = (float*)d_out;

  // workspace: two 100000x256 fp32 buffers (204.8 MB total)
  float* A = (float*)d_ws;                  // support buffer
  float* B = A + (long)N_NODES * 256;       // aggregate / hidden buffer

  const int mblocks = (N_NODES + 63) / 64;  // 1563

  // ---- Layer 1: support = x @ W1 ; agg = scatter ; h = relu(agg + b1)
  gemm_f32<<<dim3(mblocks, 256 / 64), 256, 0, stream>>>(x, W1, A, N_NODES, 128, 256);
  zero_f32<<<4096, 256, 0, stream>>>(B, (long)N_NODES * 256);
  scatter_add<256><<<32768, 256, 0, stream>>>(A, src, dst, ew, B);
  bias_act<256, true><<<2048, 256, 0, stream>>>(B, b1);

  // ---- Layer 2
  gemm_f32<<<dim3(mblocks, 256 / 64), 256, 0, stream>>>(B, W2, A, N_NODES, 256, 256);
  zero_f32<<<4096, 256, 0, stream>>>(B, (long)N_NODES * 256);
  scatter_add<256><<<32768, 256, 0, stream>>>(A, src, dst, ew, B);
  bias_act<256, true><<<2048, 256, 0, stream>>>(B, b2);

  // ---- Layer 3 (no ReLU)
  gemm_f32<<<dim3(mblocks, 128 / 64), 256, 0, stream>>>(B, W3, A, N_NODES, 256, 128);
  zero_f32<<<4096, 256, 0, stream>>>(out, (long)N_NODES * 128);
  scatter_add<128><<<32768, 256, 0, stream>>>(A, src, dst, ew, out);
  bias_act<128, false><<<2048, 256, 0, stream>>>(out, b3);
}

// Round 2
// 1375.213 us; speedup vs baseline: 2.6998x; 2.6998x over previous
//
#include <hip/hip_runtime.h>

#define N_NODES 100000
#define N_EDGES 1600000

// ---------------------------------------------------------------------------
// zero an int array
// ---------------------------------------------------------------------------
__global__ void zero_i32(int* __restrict__ p, int n) {
  int i = blockIdx.x * blockDim.x + threadIdx.x;
  const int stride = gridDim.x * blockDim.x;
  for (; i < n; i += stride) p[i] = 0;
}

// ---------------------------------------------------------------------------
// histogram of destination nodes
// ---------------------------------------------------------------------------
__global__ void hist_dst(const int* __restrict__ dst, int* __restrict__ deg) {
  int i = blockIdx.x * blockDim.x + threadIdx.x;
  const int stride = gridDim.x * blockDim.x;
  for (; i < N_EDGES; i += stride) atomicAdd(&deg[dst[i]], 1);
}

// ---------------------------------------------------------------------------
// single-block exclusive scan: start[0..n] (start[n] = E), cursor = start copy
// ---------------------------------------------------------------------------
__global__ __launch_bounds__(1024) void scan_deg(const int* __restrict__ deg,
                                                 int* __restrict__ start,
                                                 int* __restrict__ cursor,
                                                 int n) {
  __shared__ int sums[1024];
  const int t = threadIdx.x;
  const int chunk = (n + 1023) / 1024;
  const int lo = t * chunk;
  const int hi = min(lo + chunk, n);
  int s = 0;
  for (int i = lo; i < hi; ++i) s += deg[i];
  sums[t] = s;
  __syncthreads();
  // Hillis-Steele inclusive scan over the 1024 partial sums
  for (int off = 1; off < 1024; off <<= 1) {
    int v = (t >= off) ? sums[t - off] : 0;
    __syncthreads();
    sums[t] += v;
    __syncthreads();
  }
  int excl = (t == 0) ? 0 : sums[t - 1];
  for (int i = lo; i < hi; ++i) {
    const int d = deg[i];
    start[i] = excl;
    cursor[i] = excl;
    excl += d;
  }
  if (hi == n) start[n] = excl;  // total edge count
}

// ---------------------------------------------------------------------------
// scatter edges into CSR order: (src, w) sorted by dst
// ---------------------------------------------------------------------------
__global__ void edge_scatter(const int* __restrict__ src,
                             const int* __restrict__ dst,
                             const float* __restrict__ ew,
                             int* __restrict__ cursor,
                             int* __restrict__ s_sorted,
                             float* __restrict__ w_sorted) {
  int i = blockIdx.x * blockDim.x + threadIdx.x;
  const int stride = gridDim.x * blockDim.x;
  for (; i < N_EDGES; i += stride) {
    const int d = dst[i];
    const int pos = atomicAdd(&cursor[d], 1);
    s_sorted[pos] = src[i];
    w_sorted[pos] = ew[i];
  }
}

// ---------------------------------------------------------------------------
// out[n,:] = sum_{e in in-edges(n)} w_e * sup[src_e,:]
// one group of D/4 lanes per node, float4 per lane, register accumulation
// ---------------------------------------------------------------------------
template <int D>
__global__ __launch_bounds__(256) void aggregate(
    const float* __restrict__ sup, const int* __restrict__ start,
    const int* __restrict__ s_sorted, const float* __restrict__ w_sorted,
    float* __restrict__ out) {
  constexpr int L = D / 4;        // lanes per node
  constexpr int GPB = 256 / L;    // nodes per block-iteration
  const int lane = threadIdx.x % L;
  const int grp = threadIdx.x / L;
  const float4* sup4 = (const float4*)sup;
  float4* out4 = (float4*)out;
  for (int n = blockIdx.x * GPB + grp; n < N_NODES; n += gridDim.x * GPB) {
    const int s0 = start[n];
    const int s1 = start[n + 1];
    float4 acc = {0.f, 0.f, 0.f, 0.f};
    for (int i = s0; i < s1; ++i) {
      const int s = s_sorted[i];     // group-uniform -> broadcast load
      const float w = w_sorted[i];
      const float4 v = sup4[(long)s * L + lane];
      acc.x += w * v.x; acc.y += w * v.y; acc.z += w * v.z; acc.w += w * v.w;
    }
    out4[(long)n * L + lane] = acc;
  }
}

// ---------------------------------------------------------------------------
// C[N,M] = X[N,K] @ W[K,M] + b, optional ReLU.  64x64 tile, 4x4/thread, fp32
// ---------------------------------------------------------------------------
template <bool RELU>
__global__ __launch_bounds__(256) void gemm_bias(
    const float* __restrict__ X, const float* __restrict__ W,
    const float* __restrict__ b, float* __restrict__ C, int N, int K, int M) {
  __shared__ float Xs[16][68];
  __shared__ float Ws[16][68];
  const int tid = threadIdx.x;
  const int trow = tid >> 4;
  const int tcol = tid & 15;
  const int bm = blockIdx.x * 64;
  const int bn = blockIdx.y * 64;
  float acc[4][4] = {};

  for (int k0 = 0; k0 < K; k0 += 16) {
#pragma unroll
    for (int i = 0; i < 4; ++i) {
      int m = (tid >> 4) + i * 16;
      int k = tid & 15;
      int gm = bm + m;
      Xs[k][m] = (gm < N) ? X[(long)gm * K + (k0 + k)] : 0.f;
    }
#pragma unroll
    for (int i = 0; i < 4; ++i) {
      int k = (tid >> 6) + i * 4;
      int n = tid & 63;
      Ws[k][n] = W[(long)(k0 + k) * M + (bn + n)];
    }
    __syncthreads();
#pragma unroll
    for (int k = 0; k < 16; ++k) {
      float xr[4], wr[4];
#pragma unroll
      for (int i = 0; i < 4; ++i) xr[i] = Xs[k][trow * 4 + i];
#pragma unroll
      for (int j = 0; j < 4; ++j) wr[j] = Ws[k][tcol * 4 + j];
#pragma unroll
      for (int i = 0; i < 4; ++i)
#pragma unroll
        for (int j = 0; j < 4; ++j)
          acc[i][j] += xr[i] * wr[j];
    }
    __syncthreads();
  }

#pragma unroll
  for (int i = 0; i < 4; ++i) {
    const int gm = bm + trow * 4 + i;
    if (gm < N) {
#pragma unroll
      for (int j = 0; j < 4; ++j) {
        const int gn = bn + tcol * 4 + j;
        float v = acc[i][j] + b[gn];
        if (RELU) v = fmaxf(v, 0.f);
        C[(long)gm * M + gn] = v;
      }
    }
  }
}

// ---------------------------------------------------------------------------
extern "C" void kernel_launch(void* const* d_in, const int* in_sizes, int n_in,
                              void* d_out, int out_size, void* d_ws,
                              size_t ws_size, hipStream_t stream) {
  const float* x   = (const float*)d_in[0];
  const int*   src = (const int*)d_in[1];
  const int*   dst = (const int*)d_in[2];
  const float* ew  = (const float*)d_in[3];
  const float* W1  = (const float*)d_in[4];
  const float* b1  = (const float*)d_in[5];
  const float* W2  = (const float*)d_in[6];
  const float* b2  = (const float*)d_in[7];
  const float* W3  = (const float*)d_in[8];
  const float* b3  = (const float*)d_in[9];

  // CSR arrays live in d_out (51.2 MB available, 14 MB needed). They are dead
  // by the time the final GEMM overwrites d_out with the real output.
  int*   deg      = (int*)d_out;               // N
  int*   start    = deg + N_NODES;             // N+1
  int*   cursor   = start + N_NODES + 1;       // N
  int*   s_sorted = cursor + N_NODES;          // E
  float* w_sorted = (float*)(s_sorted + N_EDGES);  // E

  // ping-pong activation buffers in ws (2 x 102.4 MB)
  float* A = (float*)d_ws;
  float* B = A + (long)N_NODES * 256;

  const int mblocks = (N_NODES + 63) / 64;  // 1563

  // ---- build CSR by destination (once; reused by all 3 layers)
  zero_i32<<<391, 256, 0, stream>>>(deg, N_NODES);
  hist_dst<<<2048, 256, 0, stream>>>(dst, deg);
  scan_deg<<<1, 1024, 0, stream>>>(deg, start, cursor, N_NODES);
  edge_scatter<<<2048, 256, 0, stream>>>(src, dst, ew, cursor, s_sorted, w_sorted);

  // ---- Layer 1: h1 = relu((A x) W1 + b1)
  aggregate<128><<<12500, 256, 0, stream>>>(x, start, s_sorted, w_sorted, A);
  gemm_bias<true><<<dim3(mblocks, 4), 256, 0, stream>>>(A, W1, b1, B, N_NODES, 128, 256);

  // ---- Layer 2: h2 = relu((A h1) W2 + b2)
  aggregate<256><<<25000, 256, 0, stream>>>(B, start, s_sorted, w_sorted, A);
  gemm_bias<true><<<dim3(mblocks, 4), 256, 0, stream>>>(A, W2, b2, B, N_NODES, 256, 256);

  // ---- Layer 3: out = (A h2) W3 + b3   (writes d_out, CSR arrays now dead)
  aggregate<256><<<25000, 256, 0, stream>>>(B, start, s_sorted, w_sorted, A);
  gemm_bias<false><<<dim3(mblocks, 2), 256, 0, stream>>>(A, W3, b3, (float*)d_out,
                                                         N_NODES, 256, 128);
}

// Round 3
// 646.936 us; speedup vs baseline: 5.7390x; 2.1257x over previous
//
#include <hip/hip_runtime.h>

#define N_NODES 100000
#define N_EDGES 1600000

typedef short bf16x8 __attribute__((ext_vector_type(8)));
typedef float f32x4 __attribute__((ext_vector_type(4)));

// ---- bf16 helpers (RNE) ----------------------------------------------------
__device__ __forceinline__ unsigned short f2b(float x) {
  unsigned int u = __float_as_uint(x);
  u = (u + 0x7FFFu + ((u >> 16) & 1u)) >> 16;
  return (unsigned short)u;
}
__device__ __forceinline__ unsigned int pack2(float lo, float hi) {
  return ((unsigned int)f2b(hi) << 16) | (unsigned int)f2b(lo);
}

// ---------------------------------------------------------------------------
__global__ void zero_i32(int* __restrict__ p, int n) {
  int i = blockIdx.x * blockDim.x + threadIdx.x;
  const int stride = gridDim.x * blockDim.x;
  for (; i < n; i += stride) p[i] = 0;
}

__global__ void hist_dst(const int* __restrict__ dst, int* __restrict__ deg) {
  int i = blockIdx.x * blockDim.x + threadIdx.x;
  const int stride = gridDim.x * blockDim.x;
  for (; i < N_EDGES; i += stride) atomicAdd(&deg[dst[i]], 1);
}

// ---- 3-kernel parallel exclusive scan of deg[N] ---------------------------
__global__ __launch_bounds__(256) void scan_pass1(const int* __restrict__ deg,
                                                  int* __restrict__ start,
                                                  int* __restrict__ blockSums) {
  __shared__ int s[256];
  const int t = threadIdx.x;
  const int i = blockIdx.x * 256 + t;
  const int v = (i < N_NODES) ? deg[i] : 0;
  s[t] = v;
  __syncthreads();
  for (int off = 1; off < 256; off <<= 1) {
    int x = (t >= off) ? s[t - off] : 0;
    __syncthreads();
    s[t] += x;
    __syncthreads();
  }
  if (i < N_NODES) start[i] = s[t] - v;            // block-local exclusive
  if (t == 255) blockSums[blockIdx.x] = s[255];
}

__global__ __launch_bounds__(512) void scan_pass2(int* __restrict__ blockSums,
                                                  int nb) {
  __shared__ int s[512];
  const int t = threadIdx.x;
  const int v = (t < nb) ? blockSums[t] : 0;
  s[t] = v;
  __syncthreads();
  for (int off = 1; off < 512; off <<= 1) {
    int x = (t >= off) ? s[t - off] : 0;
    __syncthreads();
    s[t] += x;
    __syncthreads();
  }
  if (t < nb) blockSums[t] = s[t] - v;             // exclusive block offsets
}

__global__ __launch_bounds__(256) void scan_pass3(int* __restrict__ start,
                                                  int* __restrict__ cursor,
                                                  const int* __restrict__ blockSums) {
  const int i = blockIdx.x * 256 + threadIdx.x;
  if (i < N_NODES) {
    const int v = start[i] + blockSums[blockIdx.x];
    start[i] = v;
    cursor[i] = v;
  }
  if (i == 0) start[N_NODES] = N_EDGES;
}

// ---- scatter edges into CSR-by-dst order ----------------------------------
__global__ void edge_scatter(const int* __restrict__ src,
                             const int* __restrict__ dst,
                             const float* __restrict__ ew,
                             int* __restrict__ cursor,
                             int* __restrict__ s_sorted,
                             float* __restrict__ w_sorted) {
  int i = blockIdx.x * blockDim.x + threadIdx.x;
  const int stride = gridDim.x * blockDim.x;
  for (; i < N_EDGES; i += stride) {
    const int d = dst[i];
    const int pos = atomicAdd(&cursor[d], 1);
    s_sorted[pos] = src[i];
    w_sorted[pos] = ew[i];
  }
}

// ---- fp32 -> bf16 conversion (8 elems / thread) ---------------------------
__global__ void cvt_f32_bf16(const float4* __restrict__ in,
                             uint4* __restrict__ out, int n8) {
  const int i = blockIdx.x * blockDim.x + threadIdx.x;
  if (i >= n8) return;
  const float4 a = in[2 * i], b = in[2 * i + 1];
  uint4 o;
  o.x = pack2(a.x, a.y);
  o.y = pack2(a.z, a.w);
  o.z = pack2(b.x, b.y);
  o.w = pack2(b.z, b.w);
  out[i] = o;
}

// ---------------------------------------------------------------------------
// out[n,:] = sum_e w_e * sup[src_e,:]  — sup bf16, fp32 accumulate.
// F32OUT: write fp32 + bias (final layer); else write bf16.
// ---------------------------------------------------------------------------
__device__ __forceinline__ void acc8(float* acc, uint4 v, float w) {
  const unsigned int u[4] = {v.x, v.y, v.z, v.w};
#pragma unroll
  for (int q = 0; q < 4; ++q) {
    acc[2 * q]     += w * __uint_as_float(u[q] << 16);
    acc[2 * q + 1] += w * __uint_as_float(u[q] & 0xFFFF0000u);
  }
}

template <int D, bool F32OUT>
__global__ __launch_bounds__(256) void aggregate_k(
    const uint4* __restrict__ sup, const int* __restrict__ start,
    const int* __restrict__ s_sorted, const float* __restrict__ w_sorted,
    void* __restrict__ outv, const float* __restrict__ bias) {
  constexpr int L = D / 8;          // lanes per node, 16B (8 bf16) per lane
  constexpr int GPB = 256 / L;
  const int lane = threadIdx.x % L;
  const int grp  = threadIdx.x / L;
  const int n = blockIdx.x * GPB + grp;
  if (n >= N_NODES) return;

  float acc[8] = {0.f, 0.f, 0.f, 0.f, 0.f, 0.f, 0.f, 0.f};
  const int s0 = start[n];
  const int s1 = start[n + 1];
  int i = s0;
  for (; i + 1 < s1; i += 2) {
    const int sa = s_sorted[i],     sb = s_sorted[i + 1];
    const float wa = w_sorted[i],   wb = w_sorted[i + 1];
    const uint4 va = sup[(size_t)sa * L + lane];
    const uint4 vb = sup[(size_t)sb * L + lane];
    acc8(acc, va, wa);
    acc8(acc, vb, wb);
  }
  if (i < s1) {
    const uint4 v = sup[(size_t)s_sorted[i] * L + lane];
    acc8(acc, v, w_sorted[i]);
  }

  if (F32OUT) {
    float4* o = (float4*)outv + (size_t)n * (D / 4) + lane * 2;
    const float* bj = bias + lane * 8;
    float4 f0 = {acc[0] + bj[0], acc[1] + bj[1], acc[2] + bj[2], acc[3] + bj[3]};
    float4 f1 = {acc[4] + bj[4], acc[5] + bj[5], acc[6] + bj[6], acc[7] + bj[7]};
    o[0] = f0;
    o[1] = f1;
  } else {
    uint4 o;
    o.x = pack2(acc[0], acc[1]);
    o.y = pack2(acc[2], acc[3]);
    o.z = pack2(acc[4], acc[5]);
    o.w = pack2(acc[6], acc[7]);
    ((uint4*)outv)[(size_t)n * L + lane] = o;
  }
}

// ---------------------------------------------------------------------------
// C[N,M](bf16) = X[N,K](bf16) @ W[K,M](fp32, converted during LDS staging)
// (+ bias, ReLU).  Block: 128 rows x 128 cols, 4 waves (2x2), 64x64 per wave.
// W tile pre-transposed in LDS as Wt[n][k] so both fragments are k-contiguous
// 16B loads.  mfma_f32_16x16x32_bf16; C/D: col=lane&15, row=(lane>>4)*4+reg.
// ---------------------------------------------------------------------------
template <int K, bool BIAS_RELU>
__global__ __launch_bounds__(256) void gemm_mfma(
    const unsigned short* __restrict__ X, const float* __restrict__ W,
    const float* __restrict__ bias, unsigned short* __restrict__ C, int M) {
  constexpr int KP = K + 8;                       // padded LDS row (bf16 elems)
  __shared__ unsigned short Wt[128 * KP];

  const int tid = threadIdx.x;
  const int bm = blockIdx.x * 128;
  const int bn = blockIdx.y * 128;

  // stage W[k][bn+n] -> Wt[n][k] (bf16), coalesced fp32 reads
  for (int idx = tid; idx < 128 * K; idx += 256) {
    const int k = idx >> 7;
    const int n = idx & 127;
    Wt[n * KP + k] = f2b(W[(size_t)k * M + bn + n]);
  }
  __syncthreads();

  const int wid  = tid >> 6;
  const int wm   = wid >> 1;        // 0..1
  const int wn   = wid & 1;         // 0..1
  const int lane = tid & 63;
  const int lrow = lane & 15;
  const int lsel = lane >> 4;       // 0..3

  int rg[4];
#pragma unroll
  for (int m = 0; m < 4; ++m) {
    int gm = bm + wm * 64 + m * 16 + lrow;
    rg[m] = (gm < N_NODES) ? gm : (N_NODES - 1);
  }

  f32x4 acc[4][4];
#pragma unroll
  for (int m = 0; m < 4; ++m)
#pragma unroll
    for (int n = 0; n < 4; ++n) {
      acc[m][n].x = 0.f; acc[m][n].y = 0.f; acc[m][n].z = 0.f; acc[m][n].w = 0.f;
    }

  for (int k0 = 0; k0 < K; k0 += 32) {
    bf16x8 a[4], b[4];
#pragma unroll
    for (int m = 0; m < 4; ++m)
      a[m] = *reinterpret_cast<const bf16x8*>(X + (size_t)rg[m] * K + k0 + lsel * 8);
#pragma unroll
    for (int n = 0; n < 4; ++n)
      b[n] = *reinterpret_cast<const bf16x8*>(
          &Wt[(wn * 64 + n * 16 + lrow) * KP + k0 + lsel * 8]);
#pragma unroll
    for (int m = 0; m < 4; ++m)
#pragma unroll
      for (int n = 0; n < 4; ++n)
        acc[m][n] = __builtin_amdgcn_mfma_f32_16x16x32_bf16(a[m], b[n], acc[m][n], 0, 0, 0);
  }

#pragma unroll
  for (int n = 0; n < 4; ++n) {
    const int gcol = bn + wn * 64 + n * 16 + lrow;
    const float bv = BIAS_RELU ? bias[gcol] : 0.f;
#pragma unroll
    for (int m = 0; m < 4; ++m) {
      const int gmBase = bm + wm * 64 + m * 16 + lsel * 4;
#pragma unroll
      for (int j = 0; j < 4; ++j) {
        const int gm = gmBase + j;
        if (gm < N_NODES) {
          float v = acc[m][n][j] + bv;
          if (BIAS_RELU) v = fmaxf(v, 0.f);
          C[(size_t)gm * M + gcol] = f2b(v);
        }
      }
    }
  }
}

// ---------------------------------------------------------------------------
extern "C" void kernel_launch(void* const* d_in, const int* in_sizes, int n_in,
                              void* d_out, int out_size, void* d_ws,
                              size_t ws_size, hipStream_t stream) {
  const float* x   = (const float*)d_in[0];
  const int*   src = (const int*)d_in[1];
  const int*   dst = (const int*)d_in[2];
  const float* ew  = (const float*)d_in[3];
  const float* W1  = (const float*)d_in[4];
  const float* b1  = (const float*)d_in[5];
  const float* W2  = (const float*)d_in[6];
  const float* b2  = (const float*)d_in[7];
  const float* W3  = (const float*)d_in[8];
  const float* b3  = (const float*)d_in[9];

  // ws layout: two bf16 activation buffers (51.2 MB each) + CSR (~14 MB)
  unsigned short* buf0 = (unsigned short*)d_ws;
  unsigned short* buf1 = buf0 + (size_t)N_NODES * 256;
  int* csr = (int*)((char*)d_ws + 102400000);
  int*   deg       = csr;
  int*   start     = deg + N_NODES;
  int*   cursor    = start + N_NODES + 1;
  int*   blockSums = cursor + N_NODES;
  int*   s_sorted  = blockSums + 512;
  float* w_sorted  = (float*)(s_sorted + N_EDGES);

  const int NB = (N_NODES + 255) / 256;  // 391

  // ---- CSR build (once, reused by all 3 aggregations)
  zero_i32<<<NB, 256, 0, stream>>>(deg, N_NODES);
  hist_dst<<<2048, 256, 0, stream>>>(dst, deg);
  scan_pass1<<<NB, 256, 0, stream>>>(deg, start, blockSums);
  scan_pass2<<<1, 512, 0, stream>>>(blockSums, NB);
  scan_pass3<<<NB, 256, 0, stream>>>(start, cursor, blockSums);
  edge_scatter<<<2048, 256, 0, stream>>>(src, dst, ew, cursor, s_sorted, w_sorted);

  // ---- xb = bf16(x)
  cvt_f32_bf16<<<(N_NODES * 128 / 8 + 255) / 256, 256, 0, stream>>>(
      (const float4*)x, (uint4*)buf0, N_NODES * 128 / 8);

  const dim3 g2(782, 2), g1(782, 1);

  // ---- Layer 1: h1 = relu((A xb) W1 + b1)
  aggregate_k<128, false><<<6250, 256, 0, stream>>>(
      (const uint4*)buf0, start, s_sorted, w_sorted, buf1, nullptr);
  gemm_mfma<128, true><<<g2, 256, 0, stream>>>(buf1, W1, b1, buf0, 256);

  // ---- Layer 2: h2 = relu((A h1) W2 + b2)
  aggregate_k<256, false><<<12500, 256, 0, stream>>>(
      (const uint4*)buf0, start, s_sorted, w_sorted, buf1, nullptr);
  gemm_mfma<256, true><<<g2, 256, 0, stream>>>(buf1, W2, b2, buf0, 256);

  // ---- Layer 3: out = A (h2 W3) + b3   (aggregate at D=128, bias in epilogue)
  gemm_mfma<256, false><<<g1, 256, 0, stream>>>(buf0, W3, nullptr, buf1, 128);
  aggregate_k<128, true><<<6250, 256, 0, stream>>>(
      (const uint4*)buf1, start, s_sorted, w_sorted, d_out, b3);
}